// Round 1
// baseline (456.401 us; speedup 1.0000x reference)
//
#include <hip/hip_runtime.h>

// TinyMLP (2 -> 32 -> 32 -> 1, sigmoid) analytic input-gradient, fused.
//   h1 = sig(W1^T y + b1); z2 = h1 W2 + b2; h2 = sig(z2)
//   dF/dz2 = W3 * h2(1-h2)
//   dF/dh1 = W2 dz2 ; dF/dz1 = dF/dh1 * h1(1-h1)
//   dF/dy_k = sum_j W1[k,j] dz1_j
// out[i] = {x1+g1, x2+g2, y1, y2}  (row-major [B,4] == one float4/row)

#define H 32

__device__ __forceinline__ float sigmoidf_fast(float z) {
    // sigmoid(z) = 1 / (1 + 2^(-z*log2(e)))
    float e = __builtin_amdgcn_exp2f(z * -1.4426950408889634f);
    return __builtin_amdgcn_rcpf(1.0f + e);
}

__global__ __launch_bounds__(256) void tinymlp_grad_kernel(
    const float* __restrict__ x1, const float* __restrict__ x2,
    const float* __restrict__ y1, const float* __restrict__ y2,
    const float* __restrict__ W1, const float* __restrict__ b1,
    const float* __restrict__ W2, const float* __restrict__ b2,
    const float* __restrict__ W3,
    float4* __restrict__ out, int n)
{
    int i = blockIdx.x * blockDim.x + threadIdx.x;
    if (i >= n) return;

    float y1v = y1[i];
    float y2v = y2[i];

    // ---- layer 1: h1 = sigmoid(y1*W1[0,:] + y2*W1[1,:] + b1) ----
    float h1[H];
    #pragma unroll
    for (int j = 0; j < H; ++j) {
        float z = fmaf(y1v, W1[j], fmaf(y2v, W1[H + j], b1[j]));
        h1[j] = sigmoidf_fast(z);
    }

    // ---- layer 2 pre-activation: z2 = h1 @ W2 + b2 (W2 read row-major) ----
    float z2[H];
    #pragma unroll
    for (int j = 0; j < H; ++j) z2[j] = b2[j];
    #pragma unroll
    for (int k = 0; k < H; ++k) {
        float hk = h1[k];
        #pragma unroll
        for (int j = 0; j < H; ++j)
            z2[j] = fmaf(hk, W2[k * H + j], z2[j]);
    }

    // ---- dz2 = W3 * h2 * (1 - h2), stored in-place ----
    #pragma unroll
    for (int j = 0; j < H; ++j) {
        float s = sigmoidf_fast(z2[j]);
        z2[j] = W3[j] * s * (1.0f - s);
    }

    // ---- dh1 = W2 @ dz2 (row dot, W2 row-major again); fold into dY ----
    float g1 = 0.0f, g2 = 0.0f;
    #pragma unroll
    for (int k = 0; k < H; ++k) {
        float t0 = 0.0f, t1 = 0.0f;   // two accumulators to shorten dep chain
        #pragma unroll
        for (int j = 0; j < H; j += 2) {
            t0 = fmaf(W2[k * H + j],     z2[j],     t0);
            t1 = fmaf(W2[k * H + j + 1], z2[j + 1], t1);
        }
        float hk  = h1[k];
        float dz1 = (t0 + t1) * hk * (1.0f - hk);
        g1 = fmaf(W1[k],     dz1, g1);
        g2 = fmaf(W1[H + k], dz1, g2);
    }

    float4 o;
    o.x = x1[i] + g1;
    o.y = x2[i] + g2;
    o.z = y1v;
    o.w = y2v;
    out[i] = o;
}

extern "C" void kernel_launch(void* const* d_in, const int* in_sizes, int n_in,
                              void* d_out, int out_size, void* d_ws, size_t ws_size,
                              hipStream_t stream) {
    const float* x1 = (const float*)d_in[0];
    const float* x2 = (const float*)d_in[1];
    const float* y1 = (const float*)d_in[2];
    const float* y2 = (const float*)d_in[3];
    const float* W1 = (const float*)d_in[4];
    const float* b1 = (const float*)d_in[5];
    const float* W2 = (const float*)d_in[6];
    const float* b2 = (const float*)d_in[7];
    const float* W3 = (const float*)d_in[8];
    // d_in[9] = b3: constant offset, drops out of the gradient — unused.

    int n = in_sizes[0];
    const int block = 256;
    int grid = (n + block - 1) / block;
    tinymlp_grad_kernel<<<grid, block, 0, stream>>>(
        x1, x2, y1, y2, W1, b1, W2, b2, W3, (float4*)d_out, n);
}

// Round 2
// 274.616 us; speedup vs baseline: 1.6620x; 1.6620x over previous
//
#include <hip/hip_runtime.h>

// TinyMLP (2 -> 32 -> 32 -> 1, sigmoid) analytic input-gradient, fused,
// restructured onto the MFMA pipe:
//   H1[B,32]  = sig(Y W1 + b1)          -> built directly in A-frag layout (VALU)
//   Z2        = H1 @ W2                  -> 2x mfma_f32_16x16x32_bf16
//   dZ2       = W3 * s2(1-s2)            -> VALU epilogue in C-layout, LDS scatter to A-layout
//   dH1       = dZ2 @ W2^T               -> 2x mfma_f32_16x16x32_bf16
//   dZ1       = dH1 * h1(1-h1)           -> VALU, h1d via wave-private LDS
//   dY        = dZ1 @ W1^T               -> 2 fma + 16-lane butterfly reduce
// out[i] = {x1+g1, x2+g2, y1, y2}   (row-major [B,4] == float4/row)
//
// Layout facts used (verified per cdna_hip_programming.md §3 / m89/m91/m120):
//   A-frag 16x16x32: lane holds A[m=lane&15][k=(lane>>4)*8+j], j=0..7
//   B-frag 16x16x32: lane holds B[k=(lane>>4)*8+j][n=lane&15]
//   C/D:             lane holds D[row=(lane>>4)*4+r][col=lane&15], r=0..3

#define H 32

typedef __attribute__((ext_vector_type(8))) short bf16x8;
typedef __attribute__((ext_vector_type(4))) float f32x4;

__device__ __forceinline__ float sigmoidf_fast(float z) {
    float e = __builtin_amdgcn_exp2f(z * -1.4426950408889634f);
    return __builtin_amdgcn_rcpf(1.0f + e);
}

__device__ __forceinline__ short f2bf(float f) {
    union { float f; unsigned u; } v; v.f = f;
    return (short)((v.u + 0x8000u) >> 16);   // round-half-up: plenty for 0.104 abs tol
}

__global__ __launch_bounds__(256) void tinymlp_mfma_kernel(
    const float* __restrict__ x1, const float* __restrict__ x2,
    const float* __restrict__ y1, const float* __restrict__ y2,
    const float* __restrict__ W1, const float* __restrict__ b1,
    const float* __restrict__ W2, const float* __restrict__ b2,
    const float* __restrict__ W3,
    float4* __restrict__ out, int ntiles)
{
    // wave-private LDS slices: no __syncthreads needed (same-wave DS is in-order)
    __shared__ unsigned short lds_dz2[4][512];     // A-frag-order bf16: idx = lane*8+j
    __shared__ float          lds_h1d[4][16 * 36]; // row-major [16][36] (pad: 16B-aligned rows)

    const int tid  = threadIdx.x;
    const int w    = tid >> 6;
    const int lane = tid & 63;
    const int m    = lane & 15;   // A-row / B-col / C-col index
    const int q    = lane >> 4;   // quad
    const int kb   = q * 8;       // this lane's k-slice base

    // ---- preamble: wave-invariant weight fragments (loaded once) ----
    bf16x8 bW2[2], bW2T[2];
    float w1a[8], w1b[8], b1v[8];
    #pragma unroll
    for (int t = 0; t < 2; ++t) {
        #pragma unroll
        for (int j = 0; j < 8; ++j) {
            bW2[t][j]  = f2bf(W2[(kb + j) * H + m + 16 * t]);   // B[k][n]   = W2[k][n]
            bW2T[t][j] = f2bf(W2[(m + 16 * t) * H + kb + j]);   // B'[k][n]  = W2[n][k]
        }
    }
    #pragma unroll
    for (int j = 0; j < 8; ++j) {
        w1a[j] = W1[kb + j];        // W1[0][k]
        w1b[j] = W1[H + kb + j];    // W1[1][k]
        b1v[j] = b1[kb + j];
    }
    const float b2c0  = b2[m],      b2c1  = b2[m + 16];
    const float w3c0  = W3[m],      w3c1  = W3[m + 16];
    const float w1f00 = W1[m],      w1f01 = W1[m + 16];       // W1[0][col]
    const float w1f10 = W1[H + m],  w1f11 = W1[H + m + 16];   // W1[1][col]

    const int gwave  = (blockIdx.x * blockDim.x + tid) >> 6;
    const int nwaves = (gridDim.x * blockDim.x) >> 6;

    for (int tile = gwave; tile < ntiles; tile += nwaves) {
        const int base = tile * 16;

        // ---- layer 1: H1 in A-frag layout; h1d -> LDS ----
        const float y1v = y1[base + m];
        const float y2v = y2[base + m];
        bf16x8 aH;
        #pragma unroll
        for (int j = 0; j < 8; ++j) {
            float z = fmaf(y1v, w1a[j], fmaf(y2v, w1b[j], b1v[j]));
            float s = sigmoidf_fast(z);
            aH[j] = f2bf(s);
            lds_h1d[w][m * 36 + kb + j] = s * (1.0f - s);
        }

        // ---- forward GEMM: Z2 = H1 @ W2 (cols 0-15, 16-31) ----
        f32x4 accZ0 = {0.f, 0.f, 0.f, 0.f}, accZ1 = {0.f, 0.f, 0.f, 0.f};
        accZ0 = __builtin_amdgcn_mfma_f32_16x16x32_bf16(aH, bW2[0], accZ0, 0, 0, 0);
        accZ1 = __builtin_amdgcn_mfma_f32_16x16x32_bf16(aH, bW2[1], accZ1, 0, 0, 0);

        // ---- epilogue: dz2 = W3 * s2(1-s2); scatter C-layout -> A-frag-order LDS ----
        #pragma unroll
        for (int r = 0; r < 4; ++r) {
            const int row = q * 4 + r;
            {
                float s = sigmoidf_fast(accZ0[r] + b2c0);
                float d = w3c0 * s * (1.0f - s);
                const int k = m;                       // col 0-15
                lds_dz2[w][(row + 16 * (k >> 3)) * 8 + (k & 7)] = (unsigned short)f2bf(d);
            }
            {
                float s = sigmoidf_fast(accZ1[r] + b2c1);
                float d = w3c1 * s * (1.0f - s);
                const int k = m + 16;                  // col 16-31
                lds_dz2[w][(row + 16 * (k >> 3)) * 8 + (k & 7)] = (unsigned short)f2bf(d);
            }
        }

        __builtin_amdgcn_wave_barrier();   // pin DS order (same-wave LDS pipe is in-order)

        // ---- backward GEMM: dH1 = dZ2 @ W2^T ----
        const bf16x8 aD = *(const bf16x8*)&lds_dz2[w][lane * 8];
        f32x4 accD0 = {0.f, 0.f, 0.f, 0.f}, accD1 = {0.f, 0.f, 0.f, 0.f};
        accD0 = __builtin_amdgcn_mfma_f32_16x16x32_bf16(aD, bW2T[0], accD0, 0, 0, 0);
        accD1 = __builtin_amdgcn_mfma_f32_16x16x32_bf16(aD, bW2T[1], accD1, 0, 0, 0);

        // ---- dz1 = dH1 * h1d; fold W1; butterfly-reduce over the 16-lane group ----
        float p1r[4], p2r[4];
        #pragma unroll
        for (int r = 0; r < 4; ++r) {
            const int row = q * 4 + r;
            float hd0 = lds_h1d[w][row * 36 + m];
            float hd1 = lds_h1d[w][row * 36 + m + 16];
            float a = accD0[r] * hd0;
            float b = accD1[r] * hd1;
            float p1 = fmaf(a, w1f00, b * w1f01);
            float p2 = fmaf(a, w1f10, b * w1f11);
            #pragma unroll
            for (int mask = 1; mask < 16; mask <<= 1) {
                p1 += __shfl_xor(p1, mask);
                p2 += __shfl_xor(p2, mask);
            }
            p1r[r] = p1;
            p2r[r] = p2;
        }

        // ---- store: lane (q*16+c), c<4 writes row q*4+c (16 lanes, 256B coalesced) ----
        const int c = m & 3;
        const int srow = q * 4 + c;
        // shfl BEFORE divergence (source lanes must be active)
        const float y1s = __shfl(y1v, srow);
        const float y2s = __shfl(y2v, srow);
        const float g1  = (c == 0) ? p1r[0] : (c == 1) ? p1r[1] : (c == 2) ? p1r[2] : p1r[3];
        const float g2  = (c == 0) ? p2r[0] : (c == 1) ? p2r[1] : (c == 2) ? p2r[2] : p2r[3];
        if (m < 4) {
            const int row = base + srow;
            float4 o;
            o.x = x1[row] + g1;
            o.y = x2[row] + g2;
            o.z = y1s;
            o.w = y2s;
            out[row] = o;
        }
        __builtin_amdgcn_wave_barrier();   // keep next tile's LDS writes behind this tile's reads
    }
}

extern "C" void kernel_launch(void* const* d_in, const int* in_sizes, int n_in,
                              void* d_out, int out_size, void* d_ws, size_t ws_size,
                              hipStream_t stream) {
    const float* x1 = (const float*)d_in[0];
    const float* x2 = (const float*)d_in[1];
    const float* y1 = (const float*)d_in[2];
    const float* y2 = (const float*)d_in[3];
    const float* W1 = (const float*)d_in[4];
    const float* b1 = (const float*)d_in[5];
    const float* W2 = (const float*)d_in[6];
    const float* b2 = (const float*)d_in[7];
    const float* W3 = (const float*)d_in[8];
    // d_in[9] = b3: drops out of the input-gradient — unused.

    const int n = in_sizes[0];
    const int ntiles = n / 16;           // B = 4194304 -> 262144 tiles of 16 rows
    const int block = 256;               // 4 waves
    const int grid = 2048;               // 8192 waves -> 32 tiles/wave, grid-stride
    tinymlp_mfma_kernel<<<grid, block, 0, stream>>>(
        x1, x2, y1, y2, W1, b1, W2, b2, W3, (float4*)d_out, ntiles);
}

// Round 3
// 236.758 us; speedup vs baseline: 1.9277x; 1.1599x over previous
//
#include <hip/hip_runtime.h>

// TinyMLP (2 -> 32 -> 32 -> 1, sigmoid) analytic input-gradient, fused, all three
// matmul-shaped stages on the MFMA pipe:
//   MFMA#1 (x2): Z2  = H1 @ W2            (H1 built directly in A-frag layout)
//   MFMA#2 (x2): dH1 = dZ2 @ W2^T         (dZ2 via bf16 LDS scatter C->A layout)
//   MFMA#3 (x1): dY  = dZ1 @ W1rep        (W1 rows replicated even/odd cols ->
//                                          g1/g2 in C-layout, paired by shfl_xor(1))
// h1d = h1(1-h1) never touches LDS: layer-1 computes it per-lane in exactly the
// A-layout rows (row=m, k=8q+j) that the dH1 fp32 readback lands in.
//
// Layouts (16x16x32 bf16, verified m89/m91/m120):
//   A-frag: lane holds A[m=lane&15][k=(lane>>4)*8+j]
//   B-frag: lane holds B[k=(lane>>4)*8+j][n=lane&15]
//   C/D:    lane holds D[row=(lane>>4)*4+r][col=lane&15]

#define H 32

typedef __attribute__((ext_vector_type(8))) short bf16x8;
typedef __attribute__((ext_vector_type(4))) float f32x4;
typedef __attribute__((ext_vector_type(2))) float f32x2;
typedef __attribute__((ext_vector_type(2))) __bf16 bfx2;

__device__ __forceinline__ float sigmoid_r(float z, float& e) {
    // s = 1/(1+e), e = 2^(-z*log2(e));  s' = s*(1-s) = s*(e*s)
    e = __builtin_amdgcn_exp2f(z * -1.4426950408889634f);
    return __builtin_amdgcn_rcpf(1.0f + e);
}

__device__ __forceinline__ int cvt_pk_bf16(float a, float b) {
    f32x2 f; f[0] = a; f[1] = b;
    bfx2 r = __builtin_convertvector(f, bfx2);   // v_cvt_pk_bf16_f32 on gfx950
    return __builtin_bit_cast(int, r);
}

__device__ __forceinline__ unsigned short f2bf_trunc(float f) {
    unsigned u = __builtin_bit_cast(unsigned, f);
    return (unsigned short)((u + 0x8000u) >> 16);
}

__global__ __launch_bounds__(256) void tinymlp_mfma_kernel(
    const float* __restrict__ x1, const float* __restrict__ x2,
    const float* __restrict__ y1, const float* __restrict__ y2,
    const float* __restrict__ W1, const float* __restrict__ b1,
    const float* __restrict__ W2, const float* __restrict__ b2,
    const float* __restrict__ W3,
    float4* __restrict__ out, int ntiles)
{
    // wave-private slices; same-wave DS is in-order, no __syncthreads needed
    __shared__ unsigned short lds_dz2[4][512];   // bf16 A-frag order
    __shared__ float          lds_dh1[4][512];   // fp32, XOR-swizzled 8-dword blocks

    const int tid  = threadIdx.x;
    const int w    = tid >> 6;
    const int lane = tid & 63;
    const int m    = lane & 15;
    const int q    = lane >> 4;
    const int kb   = q * 8;

    // ---- wave-invariant weight fragments (built once) ----
    bf16x8 bW2_0, bW2_1, bW2T_0, bW2T_1, bW1r;
    float w1a[8], w1b[8], b1v[8];
    #pragma unroll
    for (int j = 0; j < 8; ++j) {
        bW2_0[j]  = (short)f2bf_trunc(W2[(kb + j) * H + m]);        // B[k][n]=W2[k][n]
        bW2_1[j]  = (short)f2bf_trunc(W2[(kb + j) * H + m + 16]);
        bW2T_0[j] = (short)f2bf_trunc(W2[m * H + kb + j]);          // B[k][n]=W2[n][k]
        bW2T_1[j] = (short)f2bf_trunc(W2[(m + 16) * H + kb + j]);
        bW1r[j]   = (short)f2bf_trunc(W1[(m & 1) * H + kb + j]);    // even col: W1[0,:], odd: W1[1,:]
        w1a[j] = W1[kb + j];
        w1b[j] = W1[H + kb + j];
        b1v[j] = b1[kb + j];
    }
    const float b2c0 = b2[m], b2c1 = b2[m + 16];
    const float w3c0 = W3[m], w3c1 = W3[m + 16];

    const int gwave  = (blockIdx.x * blockDim.x + tid) >> 6;
    const int nwaves = (gridDim.x * blockDim.x) >> 6;

    for (int tile = gwave; tile < ntiles; tile += nwaves) {
        const int base = tile * 16;
        const float y1v = y1[base + m];
        const float y2v = y2[base + m];

        // ---- layer 1: h1 (A-frag) + h1d kept in registers ----
        float h1d[8];
        union { int i[4]; bf16x8 v; } uaH;
        #pragma unroll
        for (int t = 0; t < 4; ++t) {
            float s2v[2];
            #pragma unroll
            for (int u = 0; u < 2; ++u) {
                const int j = 2 * t + u;
                float z = fmaf(y1v, w1a[j], fmaf(y2v, w1b[j], b1v[j]));
                float e;
                float s = sigmoid_r(z, e);
                s2v[u] = s;
                h1d[j] = s * (e * s);
            }
            uaH.i[t] = cvt_pk_bf16(s2v[0], s2v[1]);
        }
        const bf16x8 aH = uaH.v;

        // ---- forward: Z2 = H1 @ W2 ----
        f32x4 accZ0 = {0.f, 0.f, 0.f, 0.f}, accZ1 = {0.f, 0.f, 0.f, 0.f};
        accZ0 = __builtin_amdgcn_mfma_f32_16x16x32_bf16(aH, bW2_0, accZ0, 0, 0, 0);
        accZ1 = __builtin_amdgcn_mfma_f32_16x16x32_bf16(aH, bW2_1, accZ1, 0, 0, 0);

        // ---- dz2 = W3 * s2(1-s2); scatter C-layout -> A-frag bf16 LDS ----
        #pragma unroll
        for (int r = 0; r < 4; ++r) {
            const int row = q * 4 + r;
            float e0, e1;
            float s0 = sigmoid_r(accZ0[r] + b2c0, e0);
            float s1 = sigmoid_r(accZ1[r] + b2c1, e1);
            float d0 = w3c0 * s0 * (e0 * s0);
            float d1 = w3c1 * s1 * (e1 * s1);
            lds_dz2[w][(row + 16 * (m >> 3)) * 8 + (m & 7)]       = f2bf_trunc(d0);  // k=m
            lds_dz2[w][(row + 16 * ((m >> 3) + 2)) * 8 + (m & 7)] = f2bf_trunc(d1);  // k=m+16
        }
        __builtin_amdgcn_wave_barrier();

        // ---- backward: dH1 = dZ2 @ W2^T ----
        const bf16x8 aD = *(const bf16x8*)&lds_dz2[w][lane * 8];
        f32x4 accD0 = {0.f, 0.f, 0.f, 0.f}, accD1 = {0.f, 0.f, 0.f, 0.f};
        accD0 = __builtin_amdgcn_mfma_f32_16x16x32_bf16(aD, bW2T_0, accD0, 0, 0, 0);
        accD1 = __builtin_amdgcn_mfma_f32_16x16x32_bf16(aD, bW2T_1, accD1, 0, 0, 0);

        // ---- dH1 fp32 C->A transpose via LDS (8-dword blocks, XOR-swizzled) ----
        // layout: idx(row,k) = row*32 + ((k>>3) ^ (row&3))*8 + (k&7)
        #pragma unroll
        for (int r = 0; r < 4; ++r) {
            const int row = q * 4 + r;
            lds_dh1[w][row * 32 + (((m >> 3) ^ r) << 3) + (m & 7)]       = accD0[r]; // k=m
            lds_dh1[w][row * 32 + ((((m >> 3) | 2) ^ r) << 3) + (m & 7)] = accD1[r]; // k=m+16
        }
        __builtin_amdgcn_wave_barrier();
        const float* pr = &lds_dh1[w][m * 32 + ((q ^ (m & 3)) << 3)];   // row=m, k=8q+j
        const f32x4 dlo = *(const f32x4*)pr;
        const f32x4 dhi = *(const f32x4*)(pr + 4);

        // ---- dz1 = dH1 * h1d (register h1d, matching A-layout) -> A-frag bf16 ----
        union { int i[4]; bf16x8 v; } uaG;
        uaG.i[0] = cvt_pk_bf16(dlo[0] * h1d[0], dlo[1] * h1d[1]);
        uaG.i[1] = cvt_pk_bf16(dlo[2] * h1d[2], dlo[3] * h1d[3]);
        uaG.i[2] = cvt_pk_bf16(dhi[0] * h1d[4], dhi[1] * h1d[5]);
        uaG.i[3] = cvt_pk_bf16(dhi[2] * h1d[6], dhi[3] * h1d[7]);

        // ---- dY: accY[r][col] = g_{1+(col&1)}[row] ----
        f32x4 accY = {0.f, 0.f, 0.f, 0.f};
        accY = __builtin_amdgcn_mfma_f32_16x16x32_bf16(uaG.v, bW1r, accY, 0, 0, 0);

        // ---- pair g1/g2 per row with one shfl_xor, store 16 coalesced float4 ----
        const int c = m & 3;
        const float t0  = (c & 2) ? accY[2] : accY[0];
        const float t1  = (c & 2) ? accY[3] : accY[1];
        const float own = (c & 1) ? t1 : t0;   // accY[c]
        const float vs  = (c & 1) ? t0 : t1;   // accY[c^1] -> what my xor-partner needs
        const float rcv = __shfl_xor(vs, 1);   // partner's accY[c] (their col = m^1)
        const float g1 = (m & 1) ? rcv : own;
        const float g2 = (m & 1) ? own : rcv;
        const int srow = q * 4 + c;
        const float y1s = __shfl(y1v, srow);
        const float y2s = __shfl(y2v, srow);
        if (m < 4) {
            const int row = base + srow;
            float4 o;
            o.x = x1[row] + g1;
            o.y = x2[row] + g2;
            o.z = y1s;
            o.w = y2s;
            out[row] = o;
        }
        __builtin_amdgcn_wave_barrier();   // keep next tile's LDS writes behind this tile's reads
    }
}

extern "C" void kernel_launch(void* const* d_in, const int* in_sizes, int n_in,
                              void* d_out, int out_size, void* d_ws, size_t ws_size,
                              hipStream_t stream) {
    const float* x1 = (const float*)d_in[0];
    const float* x2 = (const float*)d_in[1];
    const float* y1 = (const float*)d_in[2];
    const float* y2 = (const float*)d_in[3];
    const float* W1 = (const float*)d_in[4];
    const float* b1 = (const float*)d_in[5];
    const float* W2 = (const float*)d_in[6];
    const float* b2 = (const float*)d_in[7];
    const float* W3 = (const float*)d_in[8];
    // d_in[9] = b3: drops out of the input-gradient — unused.

    const int n = in_sizes[0];
    const int ntiles = n / 16;       // B = 4194304 -> 262144 tiles
    const int block = 256;           // 4 waves
    const int grid = 2048;           // 8192 waves, grid-stride: 32 tiles/wave
    tinymlp_mfma_kernel<<<grid, block, 0, stream>>>(
        x1, x2, y1, y2, W1, b1, W2, b2, W3, (float4*)d_out, ntiles);
}

// Round 4
// 212.797 us; speedup vs baseline: 2.1448x; 1.1126x over previous
//
#include <hip/hip_runtime.h>

// TinyMLP (2 -> 32 -> 32 -> 1, sigmoid) analytic input-gradient, fused, MFMA-based.
//   MFMA#1 (x2): -log2e*Z2 = H1 @ (-log2e*W2), acc init = -log2e*b2  (exp2-ready)
//   MFMA#2 (x2): dH1 = dZ2 @ W2^T      (dZ2 via bf16 LDS scatter C->A layout)
//   MFMA#3 (x1): dY  = dZ1 @ W1rep     (g1/g2 in C-layout, paired by shfl_xor(1))
// h1d = h1(1-h1) stays in registers (layer-1 A-layout rows == dH1 readback rows).
// VALU trimmed: exp-arg scale folded into weights, b2 folded into acc init,
// h1d via v_pk_fma(-s,s,s), packed bf16 converts, pointer-increment addressing.
//
// Layouts (16x16x32 bf16, verified m89/m91/m120):
//   A-frag: lane holds A[m=lane&15][k=(lane>>4)*8+j]
//   B-frag: lane holds B[k=(lane>>4)*8+j][n=lane&15]
//   C/D:    lane holds D[row=(lane>>4)*4+r][col=lane&15]

#define H 32

typedef __attribute__((ext_vector_type(8))) short bf16x8;
typedef __attribute__((ext_vector_type(4))) float f32x4;
typedef __attribute__((ext_vector_type(2))) float f32x2;
typedef __attribute__((ext_vector_type(2))) __bf16 bfx2;

__device__ __forceinline__ int cvt_pk_bf16(float a, float b) {
    f32x2 f; f[0] = a; f[1] = b;
    bfx2 r = __builtin_convertvector(f, bfx2);   // v_cvt_pk_bf16_f32
    return __builtin_bit_cast(int, r);
}

__device__ __forceinline__ unsigned short f2bf_trunc(float f) {
    unsigned u = __builtin_bit_cast(unsigned, f);
    return (unsigned short)((u + 0x8000u) >> 16);
}

#define NLOG2E (-1.4426950408889634f)

__global__ __launch_bounds__(256) void tinymlp_mfma_kernel(
    const float* __restrict__ x1, const float* __restrict__ x2,
    const float* __restrict__ y1, const float* __restrict__ y2,
    const float* __restrict__ W1, const float* __restrict__ b1,
    const float* __restrict__ W2, const float* __restrict__ b2,
    const float* __restrict__ W3,
    float4* __restrict__ out, int ntiles)
{
    __shared__ unsigned short lds_dz2[4][512];   // bf16 A-frag order
    __shared__ float          lds_dh1[4][512];   // fp32, XOR-swizzled 8-dword blocks

    const int tid  = threadIdx.x;
    const int w    = tid >> 6;
    const int lane = tid & 63;
    const int m    = lane & 15;
    const int q    = lane >> 4;
    const int kb   = q * 8;

    // ---- wave-invariant weight fragments ----
    bf16x8 bW2s_0, bW2s_1, bW2T_0, bW2T_1, bW1r;
    float w1a[8], w1b[8], b1v[8];
    #pragma unroll
    for (int j = 0; j < 8; ++j) {
        bW2s_0[j] = (short)f2bf_trunc(NLOG2E * W2[(kb + j) * H + m]);      // scaled fwd
        bW2s_1[j] = (short)f2bf_trunc(NLOG2E * W2[(kb + j) * H + m + 16]);
        bW2T_0[j] = (short)f2bf_trunc(W2[m * H + kb + j]);                  // unscaled bwd
        bW2T_1[j] = (short)f2bf_trunc(W2[(m + 16) * H + kb + j]);
        bW1r[j]   = (short)f2bf_trunc(W1[(m & 1) * H + kb + j]);
        w1a[j] = NLOG2E * W1[kb + j];
        w1b[j] = NLOG2E * W1[H + kb + j];
        b1v[j] = NLOG2E * b1[kb + j];
    }
    const float b2s0 = NLOG2E * b2[m];
    const float b2s1 = NLOG2E * b2[m + 16];
    f32x2 w3v; w3v[0] = W3[m]; w3v[1] = W3[m + 16];

    const int gwave  = (blockIdx.x * blockDim.x + tid) >> 6;
    const int nwaves = (gridDim.x * blockDim.x) >> 6;

    // loop-carried pointers (per-lane bases, advanced by step each tile)
    const int c    = m & 3;
    const int srow = q * 4 + c;
    const long start = (long)gwave * 16;
    const long step  = (long)nwaves * 16;
    const float* py1 = y1 + start + m;
    const float* py2 = y2 + start + m;
    const float* px1 = x1 + start + srow;
    const float* px2 = x2 + start + srow;
    const float* qy1 = y1 + start + srow;
    const float* qy2 = y2 + start + srow;
    float4*      po  = out + start + srow;

    // dz2 scatter base (shorts): (row + 16*(k>>3))*8 + (k&7), row = 4q+r, k = m / m+16
    unsigned short* dzp = &lds_dz2[w][(m >> 3) * 128 + (m & 7) + q * 32];

    for (int tile = gwave; tile < ntiles; tile += nwaves) {
        const float y1v = *py1;
        const float y2v = *py2;
        float xv1 = 0.f, xv2 = 0.f, yv3 = 0.f, yv4 = 0.f;
        if (m < 4) { xv1 = *px1; xv2 = *px2; yv3 = *qy1; yv4 = *qy2; }  // early, latency-hidden

        // ---- layer 1: exp2-arg already scaled; h1 (A-frag) + h1d pairs in regs ----
        f32x2 h1dp[4];
        union { int i[4]; bf16x8 v; } uaH;
        #pragma unroll
        for (int t = 0; t < 4; ++t) {
            const int j = 2 * t;
            float z0 = fmaf(y1v, w1a[j],     fmaf(y2v, w1b[j],     b1v[j]));
            float z1 = fmaf(y1v, w1a[j + 1], fmaf(y2v, w1b[j + 1], b1v[j + 1]));
            float e0 = __builtin_amdgcn_exp2f(z0);
            float e1 = __builtin_amdgcn_exp2f(z1);
            float s0 = __builtin_amdgcn_rcpf(1.0f + e0);
            float s1 = __builtin_amdgcn_rcpf(1.0f + e1);
            f32x2 sv; sv[0] = s0; sv[1] = s1;
            h1dp[t] = __builtin_elementwise_fma(-sv, sv, sv);   // v_pk_fma_f32
            uaH.i[t] = cvt_pk_bf16(s0, s1);
        }

        // ---- forward: acc = -log2e*(H1@W2 + b2) ----
        f32x4 accZ0 = {b2s0, b2s0, b2s0, b2s0};
        f32x4 accZ1 = {b2s1, b2s1, b2s1, b2s1};
        accZ0 = __builtin_amdgcn_mfma_f32_16x16x32_bf16(uaH.v, bW2s_0, accZ0, 0, 0, 0);
        accZ1 = __builtin_amdgcn_mfma_f32_16x16x32_bf16(uaH.v, bW2s_1, accZ1, 0, 0, 0);

        // ---- dz2 = W3 * s2(1-s2); packed convert; scatter C->A bf16 LDS ----
        #pragma unroll
        for (int r = 0; r < 4; ++r) {
            float e0 = __builtin_amdgcn_exp2f(accZ0[r]);
            float e1 = __builtin_amdgcn_exp2f(accZ1[r]);
            float s0 = __builtin_amdgcn_rcpf(1.0f + e0);
            float s1 = __builtin_amdgcn_rcpf(1.0f + e1);
            f32x2 sv; sv[0] = s0; sv[1] = s1;
            f32x2 dv = __builtin_elementwise_fma(-sv, sv, sv) * w3v;  // pk_fma + pk_mul
            unsigned pk = (unsigned)cvt_pk_bf16(dv[0], dv[1]);
            dzp[r * 8]       = (unsigned short)pk;          // k = m
            dzp[r * 8 + 256] = (unsigned short)(pk >> 16);  // k = m+16
        }
        __builtin_amdgcn_wave_barrier();

        // ---- backward: dH1 = dZ2 @ W2^T ----
        const bf16x8 aD = *(const bf16x8*)&lds_dz2[w][lane * 8];
        f32x4 accD0 = {0.f, 0.f, 0.f, 0.f}, accD1 = {0.f, 0.f, 0.f, 0.f};
        accD0 = __builtin_amdgcn_mfma_f32_16x16x32_bf16(aD, bW2T_0, accD0, 0, 0, 0);
        accD1 = __builtin_amdgcn_mfma_f32_16x16x32_bf16(aD, bW2T_1, accD1, 0, 0, 0);

        // ---- dH1 fp32 C->A transpose via LDS (XOR-swizzled 8-dword blocks) ----
        #pragma unroll
        for (int r = 0; r < 4; ++r) {
            const int row = q * 4 + r;
            lds_dh1[w][row * 32 + (((m >> 3) ^ r) << 3) + (m & 7)]       = accD0[r];
            lds_dh1[w][row * 32 + ((((m >> 3) | 2) ^ r) << 3) + (m & 7)] = accD1[r];
        }
        __builtin_amdgcn_wave_barrier();
        const float* pr = &lds_dh1[w][m * 32 + ((q ^ (m & 3)) << 3)];
        const f32x4 dlo = *(const f32x4*)pr;
        const f32x4 dhi = *(const f32x4*)(pr + 4);

        // ---- dz1 = dH1 * h1d (packed) -> A-frag bf16 ----
        f32x2 p0, p1, p2, p3;
        p0[0] = dlo[0]; p0[1] = dlo[1]; p0 *= h1dp[0];
        p1[0] = dlo[2]; p1[1] = dlo[3]; p1 *= h1dp[1];
        p2[0] = dhi[0]; p2[1] = dhi[1]; p2 *= h1dp[2];
        p3[0] = dhi[2]; p3[1] = dhi[3]; p3 *= h1dp[3];
        union { int i[4]; bf16x8 v; } uaG;
        uaG.i[0] = cvt_pk_bf16(p0[0], p0[1]);
        uaG.i[1] = cvt_pk_bf16(p1[0], p1[1]);
        uaG.i[2] = cvt_pk_bf16(p2[0], p2[1]);
        uaG.i[3] = cvt_pk_bf16(p3[0], p3[1]);

        // ---- dY: accY[r][col] = g_{1+(col&1)}[row] ----
        f32x4 accY = {0.f, 0.f, 0.f, 0.f};
        accY = __builtin_amdgcn_mfma_f32_16x16x32_bf16(uaG.v, bW1r, accY, 0, 0, 0);

        // ---- pair g1/g2 with one shfl_xor; 16 coalesced float4 stores ----
        const float t0  = (c & 2) ? accY[2] : accY[0];
        const float t1  = (c & 2) ? accY[3] : accY[1];
        const float own = (c & 1) ? t1 : t0;   // accY[c]
        const float vs  = (c & 1) ? t0 : t1;   // accY[c^1]
        const float rcv = __shfl_xor(vs, 1);
        const float g1 = (m & 1) ? rcv : own;
        const float g2 = (m & 1) ? own : rcv;
        if (m < 4) {
            float4 o;
            o.x = xv1 + g1;
            o.y = xv2 + g2;
            o.z = yv3;
            o.w = yv4;
            *po = o;
        }
        __builtin_amdgcn_wave_barrier();   // next tile's LDS writes stay behind reads

        py1 += step; py2 += step; px1 += step; px2 += step;
        qy1 += step; qy2 += step; po += step;
    }
}

extern "C" void kernel_launch(void* const* d_in, const int* in_sizes, int n_in,
                              void* d_out, int out_size, void* d_ws, size_t ws_size,
                              hipStream_t stream) {
    const float* x1 = (const float*)d_in[0];
    const float* x2 = (const float*)d_in[1];
    const float* y1 = (const float*)d_in[2];
    const float* y2 = (const float*)d_in[3];
    const float* W1 = (const float*)d_in[4];
    const float* b1 = (const float*)d_in[5];
    const float* W2 = (const float*)d_in[6];
    const float* b2 = (const float*)d_in[7];
    const float* W3 = (const float*)d_in[8];
    // d_in[9] = b3: drops out of the input-gradient — unused.

    const int n = in_sizes[0];
    const int ntiles = n / 16;       // B = 4194304 -> 262144 tiles
    const int block = 256;           // 4 waves
    const int grid = 2048;           // 8192 waves, grid-stride: 32 tiles/wave
    tinymlp_mfma_kernel<<<grid, block, 0, stream>>>(
        x1, x2, y1, y2, W1, b1, W2, b2, W3, (float4*)d_out, ntiles);
}